// Round 8
// baseline (11381.859 us; speedup 1.0000x reference)
//
#include <hip/hip_runtime.h>
#include <math.h>

#define TMAX 16384
#define MDIM 16
#define SD   2048

typedef unsigned int  uint;
typedef unsigned short ushort;
typedef __attribute__((ext_vector_type(8))) short short8;
typedef __attribute__((ext_vector_type(4))) float floatx4;
typedef __attribute__((ext_vector_type(2))) uint uintx2;

// Raw workgroup barrier: LDS-only drain (no vmcnt!) so global prefetches
// stay in flight across the barrier. Correct because all cross-wave data
// exchange in the loop is through LDS (lgkmcnt).
#define BARRIER_LDS() asm volatile("s_waitcnt lgkmcnt(0)\n\ts_barrier" ::: "memory")

// ---- DPP-based full-wave (64-lane) max ----
template<int CTRL>
__device__ __forceinline__ float fmax_dpp(float v) {
    int o = __builtin_amdgcn_update_dpp(__float_as_int(v), __float_as_int(v),
                                        CTRL, 0xf, 0xf, false);
    return fmaxf(v, __int_as_float(o));
}
__device__ __forceinline__ float waveMax64(float v) {
    v = fmax_dpp<0x111>(v);
    v = fmax_dpp<0x112>(v);
    v = fmax_dpp<0x114>(v);
    v = fmax_dpp<0x118>(v);
    v = fmax_dpp<0x142>(v);
    v = fmax_dpp<0x143>(v);
    return __int_as_float(__builtin_amdgcn_readlane(__float_as_int(v), 63));
}
__device__ __forceinline__ float waveSumF(float v) {
    #pragma unroll
    for (int o = 32; o > 0; o >>= 1) v += __shfl_xor(v, o, 64);
    return v;
}

// bf16 helpers (RNE)
__device__ __forceinline__ short f2bfs(float f) {
    uint u = __float_as_uint(f);
    return (short)((u + 0x7FFFu + ((u >> 16) & 1u)) >> 16);
}
__device__ __forceinline__ uint pkbf(float a, float b) {
    uint ua = __float_as_uint(a), ub = __float_as_uint(b);
    ua = (ua + 0x7FFFu + ((ua >> 16) & 1u)) >> 16;
    ub = (ub + 0x7FFFu + ((ub >> 16) & 1u)) & 0xFFFF0000u;
    return ua | ub;
}
__device__ __forceinline__ float bfl(uint u) { return __uint_as_float(u << 16); }
__device__ __forceinline__ float bfh(uint u) { return __uint_as_float(u & 0xFFFF0000u); }

// ---- K0: x int -> float ----
__global__ __launch_bounds__(256)
void xf_kernel(const int* __restrict__ x, float* __restrict__ xf) {
    int i = blockIdx.x * 256 + threadIdx.x;
    int4 v = ((const int4*)x)[i];
    ((float4*)xf)[i] = make_float4((float)v.x, (float)v.y, (float)v.z, (float)v.w);
}

// ---- K1: SumAux -= sum_t sum_m lgamma(x+1) ----
__global__ __launch_bounds__(256)
void lgam_kernel(const int* __restrict__ x, float* __restrict__ SumAux) {
    int i = blockIdx.x * 256 + threadIdx.x;
    int4 v = ((const int4*)x)[i];
    float s = lgammaf((float)v.x + 1.f) + lgammaf((float)v.y + 1.f)
            + lgammaf((float)v.z + 1.f) + lgammaf((float)v.w + 1.f);
    s = waveSumF(s);
    if ((threadIdx.x & 63) == 0) atomicAdd(SumAux, -s);
}

// ---- K2: P_perm[t][slot] = exp(em - Dem[t]) (bf16), slot order = K3 ownership:
//      slot o = wv*256 + lane*4 + r -> state s = (4*(lane>>4) + r)*128 + 16*wv + (lane&15)
__global__ __launch_bounds__(256, 1)
void emP_kernel(const float* __restrict__ xf,
                const float* __restrict__ lam1,
                const float* __restrict__ lam2,
                const float* __restrict__ lam3,
                ushort* __restrict__ P,
                float* __restrict__ SumAux) {
    __shared__ float red[4];
    const int tid = threadIdx.x, lane = tid & 63, wv = tid >> 6;
    int sidx[8];
    #pragma unroll
    for (int j = 0; j < 8; ++j) {
        int o  = tid * 8 + j;
        int r  = o & 3;
        int ln = (o >> 2) & 63;
        int wk = (o >> 8) & 7;
        int q  = ln >> 4, nn = ln & 15;
        sidx[j] = (4 * q + r) * 128 + 16 * wk + nn;
    }
    float llc[8][16], ls[8];
    #pragma unroll
    for (int j = 0; j < 8; ++j) {
        int s = sidx[j];
        int d1 = s >> 7, d2 = (s >> 3) & 15, d3 = s & 7;
        float sum = 0.f;
        #pragma unroll
        for (int m = 0; m < 16; ++m) {
            float la = lam1[d1*16+m] + lam2[d2*16+m] + lam3[d3*16+m];
            sum += la;
            llc[j][m] = __logf(la);
        }
        ls[j] = sum;
    }
    const int t0 = blockIdx.x * 64;
    double sumD = 0.0;
    for (int ti = 0; ti < 64; ++ti) {
        int t = t0 + ti;
        const float* __restrict__ xr = xf + t * 16;
        float em[8];
        float vm = -3.4e38f;
        #pragma unroll
        for (int j = 0; j < 8; ++j) {
            float d = 0.f;
            #pragma unroll
            for (int m = 0; m < 16; ++m) d = fmaf(xr[m], llc[j][m], d);
            em[j] = d - ls[j];
            vm = fmaxf(vm, em[j]);
        }
        vm = waveMax64(vm);
        if (lane == 0) red[wv] = vm;
        __syncthreads();
        float Dem = fmaxf(fmaxf(red[0], red[1]), fmaxf(red[2], red[3]));
        uint4 w;
        w.x = pkbf(__expf(em[0]-Dem), __expf(em[1]-Dem));
        w.y = pkbf(__expf(em[2]-Dem), __expf(em[3]-Dem));
        w.z = pkbf(__expf(em[4]-Dem), __expf(em[5]-Dem));
        w.w = pkbf(__expf(em[6]-Dem), __expf(em[7]-Dem));
        *(uint4*)(P + (size_t)t * SD + tid * 8) = w;
        if (tid == 0) sumD += (double)Dem;
        __syncthreads();
    }
    if (tid == 0) atomicAdd(SumAux, (float)sumD);
}

// ---- K3: sequential recurrence, 512 threads / 8 waves ----
// Per step: S1 (1 MFMA, contract p1) -> B1 -> S23 (4 MFMAs in 2 indep chains,
// contract (p2,p3)=128 with A2(x)A3 constants) + pointwise -> B2.
// Barriers are raw lgkmcnt-only (P prefetch stays in flight); P prefetch 2-deep.
__global__ __launch_bounds__(512, 2)
void fhmm_forward_kernel(const ushort* __restrict__ P,
                         const float* __restrict__ SumAux,
                         const float* __restrict__ logA1,
                         const float* __restrict__ logA2,
                         const float* __restrict__ logA3,
                         const float* __restrict__ logpi1,
                         const float* __restrict__ logpi2,
                         const float* __restrict__ logpi3,
                         float* __restrict__ out)
{
    __shared__ __align__(16) short albf[128 * 16];
    __shared__ __align__(16) short c1b[16 * 128];
    __shared__ __align__(16) short zbuf[8];
    __shared__ float wmA[8];
    __shared__ float sD[1];
    __shared__ float sred[8];

    const int tid  = threadIdx.x;
    const int lane = tid & 63;
    const int wv   = tid >> 6;
    const int q    = lane >> 4;
    const int ml   = lane & 15;

    if (tid < 8) zbuf[tid] = 0;

    // S1 constants: B[k=p1][n=d1'] = A1[d1'=ml][p1=8q+j] (k>=16 zero)
    short8 bA1;
    #pragma unroll
    for (int j = 0; j < 8; ++j) {
        int k = 8 * q + j;
        bA1[j] = (k < 16) ? f2bfs(__expf(logA1[ml * 16 + k])) : (short)0;
    }

    // S23 constants, 4 K-chunks: global k' = 32*jc + 8q + i -> p2 = 4*jc+q, p3 = i
    const int d2p = 2 * wv + (ml >> 3);
    const int d3p = ml & 7;
    short8 bK[4];
    #pragma unroll
    for (int jc = 0; jc < 4; ++jc)
        #pragma unroll
        for (int i = 0; i < 8; ++i)
            bK[jc][i] = f2bfs(__expf(logA2[d2p * 16 + 4 * jc + q] + logA3[d3p * 8 + i]));

    // S1 A-frag: row c = 16wv+ml, kblock q (q<2 real), phys = q ^ ((ml>>3)&1)
    const short* pS1 = (q < 2)
        ? &albf[(16 * wv + ml) * 16 + ((q ^ ((ml >> 3) & 1)) << 3)] : zbuf;
    // S1 D write: C1 row = ml (=d1'), c-block = 2wv + (q>>1), phys = block ^ ml
    short* wS1 = &c1b[ml * 128 + ((((2 * wv + (q >> 1)) ^ ml) & 15) << 3) + 4 * (q & 1)];
    // S23 A-frags: row = ml (=d1), chunk jc: block = 4*jc+q, phys = block ^ ml
    const short* pS23[4];
    #pragma unroll
    for (int jc = 0; jc < 4; ++jc)
        pS23[jc] = &c1b[ml * 128 + ((((4 * jc + q) ^ ml) & 15) << 3)];
    // S23 D write: albf row cc = 16wv+ml (wave-private!), kblock swizzled
    const int cc = 16 * wv + ml;
    short* wO = &albf[cc * 16 + (((q >> 1) ^ ((cc >> 3) & 1)) << 3) + 4 * (q & 1)];

    __syncthreads();   // zbuf ready

    // ---- t = 0: alpha0 = P0 * pi ----
    double OFF = 0.0;
    float nu0, nu1, nu2, nu3;
    {
        uintx2 p0 = *(const uintx2*)(P + (size_t)tid * 4);
        float lp23 = logpi2[d2p] + logpi3[d3p];
        nu0 = bfl(p0.x) * __expf(logpi1[4 * q + 0] + lp23);
        nu1 = bfh(p0.x) * __expf(logpi1[4 * q + 1] + lp23);
        nu2 = bfl(p0.y) * __expf(logpi1[4 * q + 2] + lp23);
        nu3 = bfh(p0.y) * __expf(logpi1[4 * q + 3] + lp23);
        ((uintx2*)wO)[0] = (uintx2){pkbf(nu0, nu1), pkbf(nu2, nu3)};
        float wa = waveMax64(fmaxf(fmaxf(nu0, nu1), fmaxf(nu2, nu3)));
        if (lane == 0) wmA[wv] = wa;
        __syncthreads();
    }

    // 2-deep P prefetch: Pb0 = row t, Pb1 = row t+1 (issued; consumed later)
    uintx2 Pb0 = *(const uintx2*)(P + (size_t)1 * SD + tid * 4);
    uintx2 Pb1 = *(const uintx2*)(P + (size_t)2 * SD + tid * 4);

    // ---- sequential recurrence: 2 raw barriers/step ----
    for (int t = 1; t < TMAX; ++t) {
        int tn = (t + 2 < TMAX) ? t + 2 : TMAX - 1;
        uintx2 Pb2 = *(const uintx2*)(P + (size_t)tn * SD + tid * 4);

        // wave 0: combine prev alpha maxes -> publish inv scale, accumulate OFF
        if (wv == 0) {
            float mp = waveMax64(wmA[lane & 7]);
            if (lane == 0) {
                float mg = fmaxf(mp, 1e-30f);
                sD[0] = __builtin_amdgcn_rcpf(mg);
                OFF += (double)__logf(mg);
            }
        }

        // Stage 1: C1[d1'][c] = sum_p1 A1[d1',p1] * alpha[p1][c]
        {
            short8 af = *(const short8*)pS1;
            floatx4 acc = {0.f, 0.f, 0.f, 0.f};
            acc = __builtin_amdgcn_mfma_f32_16x16x32_bf16(af, bA1, acc, 0, 0, 0);
            ((uintx2*)wS1)[0] = (uintx2){pkbf(acc[0], acc[1]), pkbf(acc[2], acc[3])};
        }
        BARRIER_LDS();   // B1: C1 + sD ready (vmcnt stays outstanding)

        // Stage 2+3 fused: two independent MFMA chains, then combine
        {
            floatx4 a0 = {0.f, 0.f, 0.f, 0.f};
            floatx4 a1 = {0.f, 0.f, 0.f, 0.f};
            a0 = __builtin_amdgcn_mfma_f32_16x16x32_bf16(*(const short8*)pS23[0], bK[0], a0, 0, 0, 0);
            a1 = __builtin_amdgcn_mfma_f32_16x16x32_bf16(*(const short8*)pS23[1], bK[1], a1, 0, 0, 0);
            a0 = __builtin_amdgcn_mfma_f32_16x16x32_bf16(*(const short8*)pS23[2], bK[2], a0, 0, 0, 0);
            a1 = __builtin_amdgcn_mfma_f32_16x16x32_bf16(*(const short8*)pS23[3], bK[3], a1, 0, 0, 0);
            floatx4 acc = a0 + a1;
            float inv = sD[0];
            nu0 = bfl(Pb0.x) * acc[0] * inv;
            nu1 = bfh(Pb0.x) * acc[1] * inv;
            nu2 = bfl(Pb0.y) * acc[2] * inv;
            nu3 = bfh(Pb0.y) * acc[3] * inv;
            ((uintx2*)wO)[0] = (uintx2){pkbf(nu0, nu1), pkbf(nu2, nu3)};
            float wa = waveMax64(fmaxf(fmaxf(nu0, nu1), fmaxf(nu2, nu3)));
            if (lane == 0) wmA[wv] = wa;
        }
        Pb0 = Pb1; Pb1 = Pb2;
        BARRIER_LDS();   // B2: alpha (wave-private) ordering + wmA exchange
    }

    // ---- final: logp = OFF + log(sum alpha) + (SumDem - Sumlgamma) ----
    {
        float su = waveSumF(nu0 + nu1 + nu2 + nu3);
        if (lane == 0) sred[wv] = su;
        __syncthreads();
        if (tid == 0) {
            float tot = 0.f;
            #pragma unroll
            for (int i = 0; i < 8; ++i) tot += sred[i];
            out[0] = (float)(OFF + (double)__logf(tot) + (double)SumAux[0]);
        }
    }
}

extern "C" void kernel_launch(void* const* d_in, const int* in_sizes, int n_in,
                              void* d_out, int out_size, void* d_ws, size_t ws_size,
                              hipStream_t stream) {
    const int*   x      = (const int*)  d_in[0];
    const float* lam1   = (const float*)d_in[1];
    const float* lam2   = (const float*)d_in[2];
    const float* lam3   = (const float*)d_in[3];
    const float* logA1  = (const float*)d_in[4];
    const float* logA2  = (const float*)d_in[5];
    const float* logA3  = (const float*)d_in[6];
    const float* logpi1 = (const float*)d_in[7];
    const float* logpi2 = (const float*)d_in[8];
    const float* logpi3 = (const float*)d_in[9];
    float* out = (float*)d_out;

    // ws: [SumAux (256B)] [xf: 1MB] [P_perm: TMAX*2048*2B = 64MB]
    float*  SumAux = (float*)d_ws;
    float*  xf     = (float*)((char*)d_ws + 256);
    ushort* P      = (ushort*)((char*)d_ws + 256 + (size_t)TMAX * MDIM * 4);

    hipMemsetAsync(SumAux, 0, sizeof(float), stream);
    xf_kernel  <<<dim3(256), dim3(256), 0, stream>>>(x, xf);
    lgam_kernel<<<dim3(256), dim3(256), 0, stream>>>(x, SumAux);
    emP_kernel <<<dim3(TMAX / 64), dim3(256), 0, stream>>>(xf, lam1, lam2, lam3, P, SumAux);
    fhmm_forward_kernel<<<dim3(1), dim3(512), 0, stream>>>(
        P, SumAux, logA1, logA2, logA3, logpi1, logpi2, logpi3, out);
}

// Round 9
// 10195.116 us; speedup vs baseline: 1.1164x; 1.1164x over previous
//
#include <hip/hip_runtime.h>
#include <math.h>

#define TMAX 16384
#define MDIM 16
#define SD   2048

typedef unsigned int  uint;
typedef unsigned short ushort;
typedef __attribute__((ext_vector_type(8))) short short8;
typedef __attribute__((ext_vector_type(4))) float floatx4;
typedef __attribute__((ext_vector_type(2))) uint uintx2;

// ---- DPP-based full-wave (64-lane) max ----
template<int CTRL>
__device__ __forceinline__ float fmax_dpp(float v) {
    int o = __builtin_amdgcn_update_dpp(__float_as_int(v), __float_as_int(v),
                                        CTRL, 0xf, 0xf, false);
    return fmaxf(v, __int_as_float(o));
}
__device__ __forceinline__ float waveMax64(float v) {
    v = fmax_dpp<0x111>(v);
    v = fmax_dpp<0x112>(v);
    v = fmax_dpp<0x114>(v);
    v = fmax_dpp<0x118>(v);
    v = fmax_dpp<0x142>(v);
    v = fmax_dpp<0x143>(v);
    return __int_as_float(__builtin_amdgcn_readlane(__float_as_int(v), 63));
}
__device__ __forceinline__ float waveSumF(float v) {
    #pragma unroll
    for (int o = 32; o > 0; o >>= 1) v += __shfl_xor(v, o, 64);
    return v;
}

// bf16 helpers (RNE)
__device__ __forceinline__ short f2bfs(float f) {
    uint u = __float_as_uint(f);
    return (short)((u + 0x7FFFu + ((u >> 16) & 1u)) >> 16);
}
__device__ __forceinline__ uint pkbf(float a, float b) {
    uint ua = __float_as_uint(a), ub = __float_as_uint(b);
    ua = (ua + 0x7FFFu + ((ua >> 16) & 1u)) >> 16;
    ub = (ub + 0x7FFFu + ((ub >> 16) & 1u)) & 0xFFFF0000u;
    return ua | ub;
}
__device__ __forceinline__ float bfl(uint u) { return __uint_as_float(u << 16); }
__device__ __forceinline__ float bfh(uint u) { return __uint_as_float(u & 0xFFFF0000u); }

// ---- K0: x int -> float ----
__global__ __launch_bounds__(256)
void xf_kernel(const int* __restrict__ x, float* __restrict__ xf) {
    int i = blockIdx.x * 256 + threadIdx.x;
    int4 v = ((const int4*)x)[i];
    ((float4*)xf)[i] = make_float4((float)v.x, (float)v.y, (float)v.z, (float)v.w);
}

// ---- K1: SumAux -= sum_t sum_m lgamma(x+1) ----
__global__ __launch_bounds__(256)
void lgam_kernel(const int* __restrict__ x, float* __restrict__ SumAux) {
    int i = blockIdx.x * 256 + threadIdx.x;
    int4 v = ((const int4*)x)[i];
    float s = lgammaf((float)v.x + 1.f) + lgammaf((float)v.y + 1.f)
            + lgammaf((float)v.z + 1.f) + lgammaf((float)v.w + 1.f);
    s = waveSumF(s);
    if ((threadIdx.x & 63) == 0) atomicAdd(SumAux, -s);
}

// ---- K2: P_perm[t][slot] = exp(em - Dem[t]) (bf16), slot order = K3 ownership:
//      slot o = wv*256 + lane*4 + r -> state s = (4*(lane>>4) + r)*128 + 16*wv + (lane&15)
__global__ __launch_bounds__(256, 1)
void emP_kernel(const float* __restrict__ xf,
                const float* __restrict__ lam1,
                const float* __restrict__ lam2,
                const float* __restrict__ lam3,
                ushort* __restrict__ P,
                float* __restrict__ SumAux) {
    __shared__ float red[4];
    const int tid = threadIdx.x, lane = tid & 63, wv = tid >> 6;
    int sidx[8];
    #pragma unroll
    for (int j = 0; j < 8; ++j) {
        int o  = tid * 8 + j;
        int r  = o & 3;
        int ln = (o >> 2) & 63;
        int wk = (o >> 8) & 7;
        int q  = ln >> 4, nn = ln & 15;
        sidx[j] = (4 * q + r) * 128 + 16 * wk + nn;
    }
    float llc[8][16], ls[8];
    #pragma unroll
    for (int j = 0; j < 8; ++j) {
        int s = sidx[j];
        int d1 = s >> 7, d2 = (s >> 3) & 15, d3 = s & 7;
        float sum = 0.f;
        #pragma unroll
        for (int m = 0; m < 16; ++m) {
            float la = lam1[d1*16+m] + lam2[d2*16+m] + lam3[d3*16+m];
            sum += la;
            llc[j][m] = __logf(la);
        }
        ls[j] = sum;
    }
    const int t0 = blockIdx.x * 64;
    double sumD = 0.0;
    for (int ti = 0; ti < 64; ++ti) {
        int t = t0 + ti;
        const float* __restrict__ xr = xf + t * 16;
        float em[8];
        float vm = -3.4e38f;
        #pragma unroll
        for (int j = 0; j < 8; ++j) {
            float d = 0.f;
            #pragma unroll
            for (int m = 0; m < 16; ++m) d = fmaf(xr[m], llc[j][m], d);
            em[j] = d - ls[j];
            vm = fmaxf(vm, em[j]);
        }
        vm = waveMax64(vm);
        if (lane == 0) red[wv] = vm;
        __syncthreads();
        float Dem = fmaxf(fmaxf(red[0], red[1]), fmaxf(red[2], red[3]));
        uint4 w;
        w.x = pkbf(__expf(em[0]-Dem), __expf(em[1]-Dem));
        w.y = pkbf(__expf(em[2]-Dem), __expf(em[3]-Dem));
        w.z = pkbf(__expf(em[4]-Dem), __expf(em[5]-Dem));
        w.w = pkbf(__expf(em[6]-Dem), __expf(em[7]-Dem));
        *(uint4*)(P + (size_t)t * SD + tid * 8) = w;
        if (tid == 0) sumD += (double)Dem;
        __syncthreads();
    }
    if (tid == 0) atomicAdd(SumAux, (float)sumD);
}

// ---- K3: sequential recurrence, 512 threads / 8 waves, ONE barrier per step ----
// Per step t: S1 (1 MFMA, contract p1; albf wave-private read, write c1b[t&1])
//   -> __syncthreads -> per-wave wmA combine + S23 (4 MFMAs, A2(x)A3, read c1b[t&1])
//   + pointwise, write albf (wave-private) + wmA[t&1].
// c1b WAR-safe via parity double buffer; wmA race-free via parity double buffer.
__global__ __launch_bounds__(512, 2)
void fhmm_forward_kernel(const ushort* __restrict__ P,
                         const float* __restrict__ SumAux,
                         const float* __restrict__ logA1,
                         const float* __restrict__ logA2,
                         const float* __restrict__ logA3,
                         const float* __restrict__ logpi1,
                         const float* __restrict__ logpi2,
                         const float* __restrict__ logpi3,
                         float* __restrict__ out)
{
    __shared__ __align__(16) short albf[128 * 16];
    __shared__ __align__(16) short c1b[2 * 2048];   // parity double buffer
    __shared__ __align__(16) short zbuf[8];
    __shared__ float wmA[2][8];                     // parity double buffer
    __shared__ float sred[8];

    const int tid  = threadIdx.x;
    const int lane = tid & 63;
    const int wv   = tid >> 6;
    const int q    = lane >> 4;
    const int ml   = lane & 15;

    if (tid < 8) zbuf[tid] = 0;

    // S1 constants: B[k=p1][n=d1'] = A1[d1'=ml][p1=8q+j] (k>=16 zero)
    short8 bA1;
    #pragma unroll
    for (int j = 0; j < 8; ++j) {
        int k = 8 * q + j;
        bA1[j] = (k < 16) ? f2bfs(__expf(logA1[ml * 16 + k])) : (short)0;
    }

    // S23 constants, 4 K-chunks: global k' = 32*jc + 8q + i -> p2 = 4*jc+q, p3 = i
    const int d2p = 2 * wv + (ml >> 3);
    const int d3p = ml & 7;
    short8 bK[4];
    #pragma unroll
    for (int jc = 0; jc < 4; ++jc)
        #pragma unroll
        for (int i = 0; i < 8; ++i)
            bK[jc][i] = f2bfs(__expf(logA2[d2p * 16 + 4 * jc + q] + logA3[d3p * 8 + i]));

    // S1 A-frag: albf row c = 16wv+ml, kblock q (q<2 real), phys = q ^ ((ml>>3)&1)
    const short* pS1 = (q < 2)
        ? &albf[(16 * wv + ml) * 16 + ((q ^ ((ml >> 3) & 1)) << 3)] : zbuf;
    // S1 D write offset into c1b[par]: row ml, c-block (2wv+(q>>1))^ml
    const int oS1w = ml * 128 + ((((2 * wv + (q >> 1)) ^ ml) & 15) << 3) + 4 * (q & 1);
    // S23 A-frag offsets into c1b[par]: row ml, chunk jc block (4jc+q)^ml
    int o23[4];
    #pragma unroll
    for (int jc = 0; jc < 4; ++jc)
        o23[jc] = ml * 128 + ((((4 * jc + q) ^ ml) & 15) << 3);
    // S23 D write: albf row cc = 16wv+ml (wave-private), kblock swizzled
    const int cc = 16 * wv + ml;
    short* wO = &albf[cc * 16 + (((q >> 1) ^ ((cc >> 3) & 1)) << 3) + 4 * (q & 1)];

    __syncthreads();   // zbuf ready

    // ---- t = 0: alpha0 = P0 * pi ----
    double OFF = 0.0;
    float nu0, nu1, nu2, nu3;
    {
        uintx2 p0 = *(const uintx2*)(P + (size_t)tid * 4);
        float lp23 = logpi2[d2p] + logpi3[d3p];
        nu0 = bfl(p0.x) * __expf(logpi1[4 * q + 0] + lp23);
        nu1 = bfh(p0.x) * __expf(logpi1[4 * q + 1] + lp23);
        nu2 = bfl(p0.y) * __expf(logpi1[4 * q + 2] + lp23);
        nu3 = bfh(p0.y) * __expf(logpi1[4 * q + 3] + lp23);
        ((uintx2*)wO)[0] = (uintx2){pkbf(nu0, nu1), pkbf(nu2, nu3)};
        float wa = waveMax64(fmaxf(fmaxf(nu0, nu1), fmaxf(nu2, nu3)));
        if (lane == 0) wmA[0][wv] = wa;
        __syncthreads();
    }

    // 2-deep P prefetch
    uintx2 Pb0 = *(const uintx2*)(P + (size_t)1 * SD + tid * 4);
    uintx2 Pb1 = *(const uintx2*)(P + (size_t)2 * SD + tid * 4);

    // ---- sequential recurrence: ONE __syncthreads per step ----
    for (int t = 1; t < TMAX; ++t) {
        const int par = t & 1;
        short* c1cur = c1b + (par << 11);   // parity buffer base (2048 shorts)

        // Stage 1: C1[d1'][c] = sum_p1 A1[d1',p1] * alpha[p1][c]
        // (albf read is wave-private: same wave wrote these rows last step)
        {
            short8 af = *(const short8*)pS1;
            floatx4 acc = {0.f, 0.f, 0.f, 0.f};
            acc = __builtin_amdgcn_mfma_f32_16x16x32_bf16(af, bA1, acc, 0, 0, 0);
            ((uintx2*)(c1cur + oS1w))[0] = (uintx2){pkbf(acc[0], acc[1]), pkbf(acc[2], acc[3])};
        }
        __syncthreads();   // THE barrier: c1b[par] ready; wmA[par^1] visible

        // prefetch P(t+2) now: drains at next step's barrier (~1 step of cover)
        int tn = (t + 2 < TMAX) ? t + 2 : TMAX - 1;
        uintx2 Pb2 = *(const uintx2*)(P + (size_t)tn * SD + tid * 4);

        // every wave: combine prev-step alpha maxes itself (no sD broadcast)
        float mp = waveMax64(wmA[par ^ 1][lane & 7]);
        float mg = fmaxf(mp, 1e-30f);
        float inv = __builtin_amdgcn_rcpf(mg);
        if (wv == 0 && lane == 0) OFF += (double)__logf(mg);

        // Stage 2+3 fused: two independent MFMA chains over c1b[par]
        {
            floatx4 a0 = {0.f, 0.f, 0.f, 0.f};
            floatx4 a1 = {0.f, 0.f, 0.f, 0.f};
            a0 = __builtin_amdgcn_mfma_f32_16x16x32_bf16(*(const short8*)(c1cur + o23[0]), bK[0], a0, 0, 0, 0);
            a1 = __builtin_amdgcn_mfma_f32_16x16x32_bf16(*(const short8*)(c1cur + o23[1]), bK[1], a1, 0, 0, 0);
            a0 = __builtin_amdgcn_mfma_f32_16x16x32_bf16(*(const short8*)(c1cur + o23[2]), bK[2], a0, 0, 0, 0);
            a1 = __builtin_amdgcn_mfma_f32_16x16x32_bf16(*(const short8*)(c1cur + o23[3]), bK[3], a1, 0, 0, 0);
            floatx4 acc = a0 + a1;
            nu0 = bfl(Pb0.x) * acc[0] * inv;
            nu1 = bfh(Pb0.x) * acc[1] * inv;
            nu2 = bfl(Pb0.y) * acc[2] * inv;
            nu3 = bfh(Pb0.y) * acc[3] * inv;
            ((uintx2*)wO)[0] = (uintx2){pkbf(nu0, nu1), pkbf(nu2, nu3)};
            float wa = waveMax64(fmaxf(fmaxf(nu0, nu1), fmaxf(nu2, nu3)));
            if (lane == 0) wmA[par][wv] = wa;
        }
        Pb0 = Pb1; Pb1 = Pb2;
        // no second barrier: albf is wave-private; c1b WAR covered by parity;
        // wmA[par] is read only after the NEXT step's barrier.
    }

    // ---- final: logp = OFF + log(sum alpha) + (SumDem - Sumlgamma) ----
    {
        float su = waveSumF(nu0 + nu1 + nu2 + nu3);
        if (lane == 0) sred[wv] = su;
        __syncthreads();
        if (tid == 0) {
            float tot = 0.f;
            #pragma unroll
            for (int i = 0; i < 8; ++i) tot += sred[i];
            out[0] = (float)(OFF + (double)__logf(tot) + (double)SumAux[0]);
        }
    }
}

extern "C" void kernel_launch(void* const* d_in, const int* in_sizes, int n_in,
                              void* d_out, int out_size, void* d_ws, size_t ws_size,
                              hipStream_t stream) {
    const int*   x      = (const int*)  d_in[0];
    const float* lam1   = (const float*)d_in[1];
    const float* lam2   = (const float*)d_in[2];
    const float* lam3   = (const float*)d_in[3];
    const float* logA1  = (const float*)d_in[4];
    const float* logA2  = (const float*)d_in[5];
    const float* logA3  = (const float*)d_in[6];
    const float* logpi1 = (const float*)d_in[7];
    const float* logpi2 = (const float*)d_in[8];
    const float* logpi3 = (const float*)d_in[9];
    float* out = (float*)d_out;

    // ws: [SumAux (256B)] [xf: 1MB] [P_perm: TMAX*2048*2B = 64MB]
    float*  SumAux = (float*)d_ws;
    float*  xf     = (float*)((char*)d_ws + 256);
    ushort* P      = (ushort*)((char*)d_ws + 256 + (size_t)TMAX * MDIM * 4);

    hipMemsetAsync(SumAux, 0, sizeof(float), stream);
    xf_kernel  <<<dim3(256), dim3(256), 0, stream>>>(x, xf);
    lgam_kernel<<<dim3(256), dim3(256), 0, stream>>>(x, SumAux);
    emP_kernel <<<dim3(TMAX / 64), dim3(256), 0, stream>>>(xf, lam1, lam2, lam3, P, SumAux);
    fhmm_forward_kernel<<<dim3(1), dim3(512), 0, stream>>>(
        P, SumAux, logA1, logA2, logA3, logpi1, logpi2, logpi3, out);
}

// Round 10
// 9681.966 us; speedup vs baseline: 1.1756x; 1.0530x over previous
//
#include <hip/hip_runtime.h>
#include <math.h>

#define TMAX 16384
#define MDIM 16
#define SD   2048

typedef unsigned int  uint;
typedef unsigned short ushort;
typedef __attribute__((ext_vector_type(8))) short short8;
typedef __attribute__((ext_vector_type(4))) short short4v;
typedef __attribute__((ext_vector_type(4))) float floatx4;
typedef __attribute__((ext_vector_type(2))) uint uintx2;

// ---- DPP-based full-wave (64-lane) max ----
template<int CTRL>
__device__ __forceinline__ float fmax_dpp(float v) {
    int o = __builtin_amdgcn_update_dpp(__float_as_int(v), __float_as_int(v),
                                        CTRL, 0xf, 0xf, false);
    return fmaxf(v, __int_as_float(o));
}
__device__ __forceinline__ float waveMax64(float v) {
    v = fmax_dpp<0x111>(v);
    v = fmax_dpp<0x112>(v);
    v = fmax_dpp<0x114>(v);
    v = fmax_dpp<0x118>(v);
    v = fmax_dpp<0x142>(v);
    v = fmax_dpp<0x143>(v);
    return __int_as_float(__builtin_amdgcn_readlane(__float_as_int(v), 63));
}
__device__ __forceinline__ float waveSumF(float v) {
    #pragma unroll
    for (int o = 32; o > 0; o >>= 1) v += __shfl_xor(v, o, 64);
    return v;
}

// bf16 helpers (RNE)
__device__ __forceinline__ short f2bfs(float f) {
    uint u = __float_as_uint(f);
    return (short)((u + 0x7FFFu + ((u >> 16) & 1u)) >> 16);
}
__device__ __forceinline__ uint pkbf(float a, float b) {
    uint ua = __float_as_uint(a), ub = __float_as_uint(b);
    ua = (ua + 0x7FFFu + ((ua >> 16) & 1u)) >> 16;
    ub = (ub + 0x7FFFu + ((ub >> 16) & 1u)) & 0xFFFF0000u;
    return ua | ub;
}
__device__ __forceinline__ short4v pk4(float a, float b, float c, float d) {
    short4v r;
    r[0] = f2bfs(a); r[1] = f2bfs(b); r[2] = f2bfs(c); r[3] = f2bfs(d);
    return r;
}
__device__ __forceinline__ float bfl(uint u) { return __uint_as_float(u << 16); }
__device__ __forceinline__ float bfh(uint u) { return __uint_as_float(u & 0xFFFF0000u); }

// K=16 bf16 MFMA (p1 contraction is exactly 16 wide)
#if __has_builtin(__builtin_amdgcn_mfma_f32_16x16x16bf16_1k)
#define MFMA16(a, b, c) __builtin_amdgcn_mfma_f32_16x16x16bf16_1k(a, b, c, 0, 0, 0)
#else
__device__ __forceinline__ floatx4 mfma16_asm(short4v a, short4v b, floatx4 c) {
    asm volatile("v_mfma_f32_16x16x16_bf16 %0, %1, %2, %0\n\t"
                 "s_nop 7\n\ts_nop 7"
                 : "+v"(c) : "v"(a), "v"(b));
    return c;
}
#define MFMA16(a, b, c) mfma16_asm(a, b, c)
#endif

// ---- K0: x int -> float ----
__global__ __launch_bounds__(256)
void xf_kernel(const int* __restrict__ x, float* __restrict__ xf) {
    int i = blockIdx.x * 256 + threadIdx.x;
    int4 v = ((const int4*)x)[i];
    ((float4*)xf)[i] = make_float4((float)v.x, (float)v.y, (float)v.z, (float)v.w);
}

// ---- K1: SumAux -= sum_t sum_m lgamma(x+1) ----
__global__ __launch_bounds__(256)
void lgam_kernel(const int* __restrict__ x, float* __restrict__ SumAux) {
    int i = blockIdx.x * 256 + threadIdx.x;
    int4 v = ((const int4*)x)[i];
    float s = lgammaf((float)v.x + 1.f) + lgammaf((float)v.y + 1.f)
            + lgammaf((float)v.z + 1.f) + lgammaf((float)v.w + 1.f);
    s = waveSumF(s);
    if ((threadIdx.x & 63) == 0) atomicAdd(SumAux, -s);
}

// ---- K2: P_perm[t][slot] = exp(em - Dem[t]) (bf16), slot order = K3 ownership:
//      slot o = wv*256 + lane*4 + r -> state s = (4*(lane>>4) + r)*128 + 16*wv + (lane&15)
__global__ __launch_bounds__(256, 1)
void emP_kernel(const float* __restrict__ xf,
                const float* __restrict__ lam1,
                const float* __restrict__ lam2,
                const float* __restrict__ lam3,
                ushort* __restrict__ P,
                float* __restrict__ SumAux) {
    __shared__ float red[4];
    const int tid = threadIdx.x, lane = tid & 63, wv = tid >> 6;
    int sidx[8];
    #pragma unroll
    for (int j = 0; j < 8; ++j) {
        int o  = tid * 8 + j;
        int r  = o & 3;
        int ln = (o >> 2) & 63;
        int wk = (o >> 8) & 7;
        int q  = ln >> 4, nn = ln & 15;
        sidx[j] = (4 * q + r) * 128 + 16 * wk + nn;
    }
    float llc[8][16], ls[8];
    #pragma unroll
    for (int j = 0; j < 8; ++j) {
        int s = sidx[j];
        int d1 = s >> 7, d2 = (s >> 3) & 15, d3 = s & 7;
        float sum = 0.f;
        #pragma unroll
        for (int m = 0; m < 16; ++m) {
            float la = lam1[d1*16+m] + lam2[d2*16+m] + lam3[d3*16+m];
            sum += la;
            llc[j][m] = __logf(la);
        }
        ls[j] = sum;
    }
    const int t0 = blockIdx.x * 64;
    double sumD = 0.0;
    for (int ti = 0; ti < 64; ++ti) {
        int t = t0 + ti;
        const float* __restrict__ xr = xf + t * 16;
        float em[8];
        float vm = -3.4e38f;
        #pragma unroll
        for (int j = 0; j < 8; ++j) {
            float d = 0.f;
            #pragma unroll
            for (int m = 0; m < 16; ++m) d = fmaf(xr[m], llc[j][m], d);
            em[j] = d - ls[j];
            vm = fmaxf(vm, em[j]);
        }
        vm = waveMax64(vm);
        if (lane == 0) red[wv] = vm;
        __syncthreads();
        float Dem = fmaxf(fmaxf(red[0], red[1]), fmaxf(red[2], red[3]));
        uint4 w;
        w.x = pkbf(__expf(em[0]-Dem), __expf(em[1]-Dem));
        w.y = pkbf(__expf(em[2]-Dem), __expf(em[3]-Dem));
        w.z = pkbf(__expf(em[4]-Dem), __expf(em[5]-Dem));
        w.w = pkbf(__expf(em[6]-Dem), __expf(em[7]-Dem));
        *(uint4*)(P + (size_t)t * SD + tid * 8) = w;
        if (tid == 0) sumD += (double)Dem;
        __syncthreads();
    }
    if (tid == 0) atomicAdd(SumAux, (float)sumD);
}

// ---- K3: sequential recurrence, 512 threads / 8 waves, 1 barrier/step ----
// alpha lives in REGISTERS: S23's D (lane (q,ml): alpha'[p1=4q+r][c=16wv+ml])
// IS the A-fragment of mfma_f32_16x16x16_bf16 for S1 (A[m=ml][k=4q+r]).
// Per step: pack nu -> S1 (1 K16 MFMA) -> ds_write_b64 C1[par] -> barrier ->
// S23 (4 b128 reads + 4 MFMAs, A2(x)A3 in B) + pointwise -> nu regs.
__global__ __launch_bounds__(512, 2)
void fhmm_forward_kernel(const ushort* __restrict__ P,
                         const float* __restrict__ SumAux,
                         const float* __restrict__ logA1,
                         const float* __restrict__ logA2,
                         const float* __restrict__ logA3,
                         const float* __restrict__ logpi1,
                         const float* __restrict__ logpi2,
                         const float* __restrict__ logpi3,
                         float* __restrict__ out)
{
    __shared__ __align__(16) short c1b[2 * 2048];   // parity double buffer
    __shared__ float wmA[2][8];                     // parity double buffer
    __shared__ float sred[8];

    const int tid  = threadIdx.x;
    const int lane = tid & 63;
    const int wv   = tid >> 6;
    const int q    = lane >> 4;
    const int ml   = lane & 15;

    // S1 constants (K=16): B[k=p1=4q+j][n=d1'=ml] = exp(logA1[ml][4q+j])
    short4v bA1k;
    #pragma unroll
    for (int j = 0; j < 4; ++j)
        bA1k[j] = f2bfs(__expf(logA1[ml * 16 + 4 * q + j]));

    // S23 constants, 4 K-chunks: k' = 32jc + 8q + i -> p2 = 4jc+q, p3 = i;
    // n = ml -> d2' = 2wv + (ml>>3), d3' = ml&7
    const int d2p = 2 * wv + (ml >> 3);
    const int d3p = ml & 7;
    short8 bK[4];
    #pragma unroll
    for (int jc = 0; jc < 4; ++jc)
        #pragma unroll
        for (int i = 0; i < 8; ++i)
            bK[jc][i] = f2bfs(__expf(logA2[d2p * 16 + 4 * jc + q] + logA3[d3p * 8 + i]));

    // S1 D write offset into c1b[par]: row ml, c-block (2wv+(q>>1))^ml  [R9-verified]
    const int oS1w = ml * 128 + ((((2 * wv + (q >> 1)) ^ ml) & 15) << 3) + 4 * (q & 1);
    // S23 A-frag offsets into c1b[par]: row ml, chunk jc block (4jc+q)^ml [R9-verified]
    int o23[4];
    #pragma unroll
    for (int jc = 0; jc < 4; ++jc)
        o23[jc] = ml * 128 + ((((4 * jc + q) ^ ml) & 15) << 3);

    // ---- t = 0: alpha0 = P0 * pi, straight into registers ----
    double OFF = 0.0;
    float nu0, nu1, nu2, nu3;
    {
        uintx2 p0 = *(const uintx2*)(P + (size_t)tid * 4);
        float lp23 = logpi2[d2p] + logpi3[d3p];
        nu0 = bfl(p0.x) * __expf(logpi1[4 * q + 0] + lp23);
        nu1 = bfh(p0.x) * __expf(logpi1[4 * q + 1] + lp23);
        nu2 = bfl(p0.y) * __expf(logpi1[4 * q + 2] + lp23);
        nu3 = bfh(p0.y) * __expf(logpi1[4 * q + 3] + lp23);
        float wa = waveMax64(fmaxf(fmaxf(nu0, nu1), fmaxf(nu2, nu3)));
        if (lane == 0) wmA[0][wv] = wa;
        __syncthreads();
    }

    // 2-deep P prefetch
    uintx2 Pb0 = *(const uintx2*)(P + (size_t)1 * SD + tid * 4);
    uintx2 Pb1 = *(const uintx2*)(P + (size_t)2 * SD + tid * 4);

    // ---- sequential recurrence: ONE __syncthreads per step ----
    for (int t = 1; t < TMAX; ++t) {
        const int par = t & 1;
        short* c1cur = c1b + (par << 11);

        // Stage 1 from registers: C1[c][d1'] = sum_p1 alpha'[p1][c] * A1[d1'][p1]
        {
            short4v af = pk4(nu0, nu1, nu2, nu3);     // A[m=ml][k=4q+r]
            floatx4 acc = {0.f, 0.f, 0.f, 0.f};
            acc = MFMA16(af, bA1k, acc);
            ((uintx2*)(c1cur + oS1w))[0] = (uintx2){pkbf(acc[0], acc[1]), pkbf(acc[2], acc[3])};
        }
        __syncthreads();   // THE barrier: c1b[par] ready; wmA[par^1] visible

        // prefetch P(t+2): drains at next step's barrier
        int tn = (t + 2 < TMAX) ? t + 2 : TMAX - 1;
        uintx2 Pb2 = *(const uintx2*)(P + (size_t)tn * SD + tid * 4);

        // every wave: combine prev-step alpha maxes
        float mp = waveMax64(wmA[par ^ 1][lane & 7]);
        float mg = fmaxf(mp, 1e-30f);
        float inv = __builtin_amdgcn_rcpf(mg);
        if (wv == 0 && lane == 0) OFF += (double)__logf(mg);

        // Stage 2+3 fused: two independent MFMA chains over c1b[par]
        {
            floatx4 a0 = {0.f, 0.f, 0.f, 0.f};
            floatx4 a1 = {0.f, 0.f, 0.f, 0.f};
            a0 = __builtin_amdgcn_mfma_f32_16x16x32_bf16(*(const short8*)(c1cur + o23[0]), bK[0], a0, 0, 0, 0);
            a1 = __builtin_amdgcn_mfma_f32_16x16x32_bf16(*(const short8*)(c1cur + o23[1]), bK[1], a1, 0, 0, 0);
            a0 = __builtin_amdgcn_mfma_f32_16x16x32_bf16(*(const short8*)(c1cur + o23[2]), bK[2], a0, 0, 0, 0);
            a1 = __builtin_amdgcn_mfma_f32_16x16x32_bf16(*(const short8*)(c1cur + o23[3]), bK[3], a1, 0, 0, 0);
            floatx4 acc = a0 + a1;
            nu0 = bfl(Pb0.x) * acc[0] * inv;
            nu1 = bfh(Pb0.x) * acc[1] * inv;
            nu2 = bfl(Pb0.y) * acc[2] * inv;
            nu3 = bfh(Pb0.y) * acc[3] * inv;
            float wa = waveMax64(fmaxf(fmaxf(nu0, nu1), fmaxf(nu2, nu3)));
            if (lane == 0) wmA[par][wv] = wa;
        }
        Pb0 = Pb1; Pb1 = Pb2;
        // no second barrier: alpha is in registers; c1b WAR covered by parity;
        // wmA[par] read only after the NEXT step's barrier.
    }

    // ---- final: logp = OFF + log(sum alpha) + (SumDem - Sumlgamma) ----
    {
        float su = waveSumF(nu0 + nu1 + nu2 + nu3);
        if (lane == 0) sred[wv] = su;
        __syncthreads();
        if (tid == 0) {
            float tot = 0.f;
            #pragma unroll
            for (int i = 0; i < 8; ++i) tot += sred[i];
            out[0] = (float)(OFF + (double)__logf(tot) + (double)SumAux[0]);
        }
    }
}

extern "C" void kernel_launch(void* const* d_in, const int* in_sizes, int n_in,
                              void* d_out, int out_size, void* d_ws, size_t ws_size,
                              hipStream_t stream) {
    const int*   x      = (const int*)  d_in[0];
    const float* lam1   = (const float*)d_in[1];
    const float* lam2   = (const float*)d_in[2];
    const float* lam3   = (const float*)d_in[3];
    const float* logA1  = (const float*)d_in[4];
    const float* logA2  = (const float*)d_in[5];
    const float* logA3  = (const float*)d_in[6];
    const float* logpi1 = (const float*)d_in[7];
    const float* logpi2 = (const float*)d_in[8];
    const float* logpi3 = (const float*)d_in[9];
    float* out = (float*)d_out;

    // ws: [SumAux (256B)] [xf: 1MB] [P_perm: TMAX*2048*2B = 64MB]
    float*  SumAux = (float*)d_ws;
    float*  xf     = (float*)((char*)d_ws + 256);
    ushort* P      = (ushort*)((char*)d_ws + 256 + (size_t)TMAX * MDIM * 4);

    hipMemsetAsync(SumAux, 0, sizeof(float), stream);
    xf_kernel  <<<dim3(256), dim3(256), 0, stream>>>(x, xf);
    lgam_kernel<<<dim3(256), dim3(256), 0, stream>>>(x, SumAux);
    emP_kernel <<<dim3(TMAX / 64), dim3(256), 0, stream>>>(xf, lam1, lam2, lam3, P, SumAux);
    fhmm_forward_kernel<<<dim3(1), dim3(512), 0, stream>>>(
        P, SumAux, logA1, logA2, logA3, logpi1, logpi2, logpi3, out);
}

// Round 11
// 270.122 us; speedup vs baseline: 42.1360x; 35.8429x over previous
//
#include <hip/hip_runtime.h>
#include <math.h>

#define TMAX 16384
#define MDIM 16
#define SD   2048
#define CHK  128     // number of parallel chunks
#define CLEN 128     // steps per chunk (CHK*CLEN == TMAX)
#define WUP  64      // warmup steps per chunk (boundary forgetting)

typedef unsigned int  uint;
typedef unsigned short ushort;
typedef __attribute__((ext_vector_type(8))) short short8;
typedef __attribute__((ext_vector_type(4))) short short4v;
typedef __attribute__((ext_vector_type(4))) float floatx4;
typedef __attribute__((ext_vector_type(2))) uint uintx2;

// ---- DPP-based full-wave (64-lane) max ----
template<int CTRL>
__device__ __forceinline__ float fmax_dpp(float v) {
    int o = __builtin_amdgcn_update_dpp(__float_as_int(v), __float_as_int(v),
                                        CTRL, 0xf, 0xf, false);
    return fmaxf(v, __int_as_float(o));
}
__device__ __forceinline__ float waveMax64(float v) {
    v = fmax_dpp<0x111>(v);
    v = fmax_dpp<0x112>(v);
    v = fmax_dpp<0x114>(v);
    v = fmax_dpp<0x118>(v);
    v = fmax_dpp<0x142>(v);
    v = fmax_dpp<0x143>(v);
    return __int_as_float(__builtin_amdgcn_readlane(__float_as_int(v), 63));
}
__device__ __forceinline__ float waveSumF(float v) {
    #pragma unroll
    for (int o = 32; o > 0; o >>= 1) v += __shfl_xor(v, o, 64);
    return v;
}

// bf16 helpers (RNE)
__device__ __forceinline__ short f2bfs(float f) {
    uint u = __float_as_uint(f);
    return (short)((u + 0x7FFFu + ((u >> 16) & 1u)) >> 16);
}
__device__ __forceinline__ uint pkbf(float a, float b) {
    uint ua = __float_as_uint(a), ub = __float_as_uint(b);
    ua = (ua + 0x7FFFu + ((ua >> 16) & 1u)) >> 16;
    ub = (ub + 0x7FFFu + ((ub >> 16) & 1u)) & 0xFFFF0000u;
    return ua | ub;
}
__device__ __forceinline__ short4v pk4(float a, float b, float c, float d) {
    short4v r;
    r[0] = f2bfs(a); r[1] = f2bfs(b); r[2] = f2bfs(c); r[3] = f2bfs(d);
    return r;
}
__device__ __forceinline__ float bfl(uint u) { return __uint_as_float(u << 16); }
__device__ __forceinline__ float bfh(uint u) { return __uint_as_float(u & 0xFFFF0000u); }

// K=16 bf16 MFMA
#if __has_builtin(__builtin_amdgcn_mfma_f32_16x16x16bf16_1k)
#define MFMA16(a, b, c) __builtin_amdgcn_mfma_f32_16x16x16bf16_1k(a, b, c, 0, 0, 0)
#else
__device__ __forceinline__ floatx4 mfma16_asm(short4v a, short4v b, floatx4 c) {
    asm volatile("v_mfma_f32_16x16x16_bf16 %0, %1, %2, %0\n\t"
                 "s_nop 7\n\ts_nop 7"
                 : "+v"(c) : "v"(a), "v"(b));
    return c;
}
#define MFMA16(a, b, c) mfma16_asm(a, b, c)
#endif

// ---- K0: x int -> float ----
__global__ __launch_bounds__(256)
void xf_kernel(const int* __restrict__ x, float* __restrict__ xf) {
    int i = blockIdx.x * 256 + threadIdx.x;
    int4 v = ((const int4*)x)[i];
    ((float4*)xf)[i] = make_float4((float)v.x, (float)v.y, (float)v.z, (float)v.w);
}

// ---- K1: SumAux -= sum_t sum_m lgamma(x+1) ----
__global__ __launch_bounds__(256)
void lgam_kernel(const int* __restrict__ x, float* __restrict__ SumAux) {
    int i = blockIdx.x * 256 + threadIdx.x;
    int4 v = ((const int4*)x)[i];
    float s = lgammaf((float)v.x + 1.f) + lgammaf((float)v.y + 1.f)
            + lgammaf((float)v.z + 1.f) + lgammaf((float)v.w + 1.f);
    s = waveSumF(s);
    if ((threadIdx.x & 63) == 0) atomicAdd(SumAux, -s);
}

// ---- K2: P_perm[t][slot] = exp(em - Dem[t]) (bf16); 1024 blocks x 16 steps ----
__global__ __launch_bounds__(256, 1)
void emP_kernel(const float* __restrict__ xf,
                const float* __restrict__ lam1,
                const float* __restrict__ lam2,
                const float* __restrict__ lam3,
                ushort* __restrict__ P,
                float* __restrict__ SumAux) {
    __shared__ float red[4];
    const int tid = threadIdx.x, lane = tid & 63, wv = tid >> 6;
    int sidx[8];
    #pragma unroll
    for (int j = 0; j < 8; ++j) {
        int o  = tid * 8 + j;
        int r  = o & 3;
        int ln = (o >> 2) & 63;
        int wk = (o >> 8) & 7;
        int q  = ln >> 4, nn = ln & 15;
        sidx[j] = (4 * q + r) * 128 + 16 * wk + nn;
    }
    float llc[8][16], ls[8];
    #pragma unroll
    for (int j = 0; j < 8; ++j) {
        int s = sidx[j];
        int d1 = s >> 7, d2 = (s >> 3) & 15, d3 = s & 7;
        float sum = 0.f;
        #pragma unroll
        for (int m = 0; m < 16; ++m) {
            float la = lam1[d1*16+m] + lam2[d2*16+m] + lam3[d3*16+m];
            sum += la;
            llc[j][m] = __logf(la);
        }
        ls[j] = sum;
    }
    const int t0 = blockIdx.x * 16;
    double sumD = 0.0;
    for (int ti = 0; ti < 16; ++ti) {
        int t = t0 + ti;
        const float* __restrict__ xr = xf + t * 16;
        float em[8];
        float vm = -3.4e38f;
        #pragma unroll
        for (int j = 0; j < 8; ++j) {
            float d = 0.f;
            #pragma unroll
            for (int m = 0; m < 16; ++m) d = fmaf(xr[m], llc[j][m], d);
            em[j] = d - ls[j];
            vm = fmaxf(vm, em[j]);
        }
        vm = waveMax64(vm);
        if (lane == 0) red[wv] = vm;
        __syncthreads();
        float Dem = fmaxf(fmaxf(red[0], red[1]), fmaxf(red[2], red[3]));
        uint4 w;
        w.x = pkbf(__expf(em[0]-Dem), __expf(em[1]-Dem));
        w.y = pkbf(__expf(em[2]-Dem), __expf(em[3]-Dem));
        w.z = pkbf(__expf(em[4]-Dem), __expf(em[5]-Dem));
        w.w = pkbf(__expf(em[6]-Dem), __expf(em[7]-Dem));
        *(uint4*)(P + (size_t)t * SD + tid * 8) = w;
        if (tid == 0) sumD += (double)Dem;
        __syncthreads();
    }
    if (tid == 0) atomicAdd(SumAux, (float)sumD);
}

// ---- K3: CHUNKED forward recurrence. grid = CHK blocks x 512 threads.
// Chunk c: warm-start beta = P_row(t0) at t0 = c*CLEN - WUP (chunk 0: exact
// pi init), run R10's verified step loop to t_end-1; accumulate log(max beta_t)
// only for t >= c*CLEN (producer-assignment makes telescoping exact; each
// step divides by its input's max so the chunk is invariant to warm-start
// scale). Last chunk adds log(sum beta); chunk 0 adds SumAux. atomicAdd-combine.
__global__ __launch_bounds__(512, 2)
void fhmm_chunk_kernel(const ushort* __restrict__ P,
                       const float* __restrict__ SumAux,
                       const float* __restrict__ logA1,
                       const float* __restrict__ logA2,
                       const float* __restrict__ logA3,
                       const float* __restrict__ logpi1,
                       const float* __restrict__ logpi2,
                       const float* __restrict__ logpi3,
                       float* __restrict__ out)
{
    __shared__ __align__(16) short c1b[2 * 2048];   // parity double buffer
    __shared__ float wmA[2][8];                     // parity double buffer
    __shared__ float sred[8];

    const int tid  = threadIdx.x;
    const int lane = tid & 63;
    const int wv   = tid >> 6;
    const int q    = lane >> 4;
    const int ml   = lane & 15;

    const int c    = blockIdx.x;
    const int tw0  = (c == 0) ? 0 : c * CLEN - WUP;
    const int tEnd = (c + 1) * CLEN;
    const int bAcc = c * CLEN;     // accumulate log when (t-1) >= bAcc i.e. t > bAcc

    // S1 constants (K=16): B[k=p1=4q+j][n=d1'=ml] = exp(logA1[ml][4q+j])
    short4v bA1k;
    #pragma unroll
    for (int j = 0; j < 4; ++j)
        bA1k[j] = f2bfs(__expf(logA1[ml * 16 + 4 * q + j]));

    // S23 constants, 4 K-chunks: k' = 32jc + 8q + i -> p2 = 4jc+q, p3 = i
    const int d2p = 2 * wv + (ml >> 3);
    const int d3p = ml & 7;
    short8 bK[4];
    #pragma unroll
    for (int jc = 0; jc < 4; ++jc)
        #pragma unroll
        for (int i = 0; i < 8; ++i)
            bK[jc][i] = f2bfs(__expf(logA2[d2p * 16 + 4 * jc + q] + logA3[d3p * 8 + i]));

    // S1 D write offset into c1b[par]  [R9/R10-verified]
    const int oS1w = ml * 128 + ((((2 * wv + (q >> 1)) ^ ml) & 15) << 3) + 4 * (q & 1);
    // S23 A-frag offsets [R9/R10-verified]
    int o23[4];
    #pragma unroll
    for (int jc = 0; jc < 4; ++jc)
        o23[jc] = ml * 128 + ((((4 * jc + q) ^ ml) & 15) << 3);

    // ---- init beta at t = tw0 ----
    double OFF = 0.0;
    float nu0, nu1, nu2, nu3;
    {
        uintx2 p0 = *(const uintx2*)(P + (size_t)tw0 * SD + tid * 4);
        if (c == 0) {   // exact: beta_0 = P_0 * pi
            float lp23 = logpi2[d2p] + logpi3[d3p];
            nu0 = bfl(p0.x) * __expf(logpi1[4 * q + 0] + lp23);
            nu1 = bfh(p0.x) * __expf(logpi1[4 * q + 1] + lp23);
            nu2 = bfl(p0.y) * __expf(logpi1[4 * q + 2] + lp23);
            nu3 = bfh(p0.y) * __expf(logpi1[4 * q + 3] + lp23);
        } else {        // warm-start: beta = P row (arbitrary positive scale)
            nu0 = bfl(p0.x); nu1 = bfh(p0.x);
            nu2 = bfl(p0.y); nu3 = bfh(p0.y);
        }
        float wa = waveMax64(fmaxf(fmaxf(nu0, nu1), fmaxf(nu2, nu3)));
        if (lane == 0) wmA[tw0 & 1][wv] = wa;
        __syncthreads();
    }

    // 2-deep P prefetch
    uintx2 Pb0 = *(const uintx2*)(P + (size_t)(tw0 + 1) * SD + tid * 4);
    uintx2 Pb1 = *(const uintx2*)(P + (size_t)(tw0 + 2) * SD + tid * 4);

    // ---- step loop (R10-verified body + accumulate guard) ----
    for (int t = tw0 + 1; t < tEnd; ++t) {
        const int par = t & 1;
        short* c1cur = c1b + (par << 11);

        // Stage 1 from registers
        {
            short4v af = pk4(nu0, nu1, nu2, nu3);
            floatx4 acc = {0.f, 0.f, 0.f, 0.f};
            acc = MFMA16(af, bA1k, acc);
            ((uintx2*)(c1cur + oS1w))[0] = (uintx2){pkbf(acc[0], acc[1]), pkbf(acc[2], acc[3])};
        }
        __syncthreads();

        int tn = (t + 2 < TMAX) ? t + 2 : TMAX - 1;
        uintx2 Pb2 = *(const uintx2*)(P + (size_t)tn * SD + tid * 4);

        float mp = waveMax64(wmA[par ^ 1][lane & 7]);
        float mg = fmaxf(mp, 1e-30f);
        float inv = __builtin_amdgcn_rcpf(mg);
        if (wv == 0 && lane == 0 && t > bAcc) OFF += (double)__logf(mg);

        // Stage 2+3 fused
        {
            floatx4 a0 = {0.f, 0.f, 0.f, 0.f};
            floatx4 a1 = {0.f, 0.f, 0.f, 0.f};
            a0 = __builtin_amdgcn_mfma_f32_16x16x32_bf16(*(const short8*)(c1cur + o23[0]), bK[0], a0, 0, 0, 0);
            a1 = __builtin_amdgcn_mfma_f32_16x16x32_bf16(*(const short8*)(c1cur + o23[1]), bK[1], a1, 0, 0, 0);
            a0 = __builtin_amdgcn_mfma_f32_16x16x32_bf16(*(const short8*)(c1cur + o23[2]), bK[2], a0, 0, 0, 0);
            a1 = __builtin_amdgcn_mfma_f32_16x16x32_bf16(*(const short8*)(c1cur + o23[3]), bK[3], a1, 0, 0, 0);
            floatx4 acc = a0 + a1;
            nu0 = bfl(Pb0.x) * acc[0] * inv;
            nu1 = bfh(Pb0.x) * acc[1] * inv;
            nu2 = bfl(Pb0.y) * acc[2] * inv;
            nu3 = bfh(Pb0.y) * acc[3] * inv;
            float wa = waveMax64(fmaxf(fmaxf(nu0, nu1), fmaxf(nu2, nu3)));
            if (lane == 0) wmA[par][wv] = wa;
        }
        Pb0 = Pb1; Pb1 = Pb2;
    }
    __syncthreads();   // wmA[lpar] / final nu stable

    const int lpar = (tEnd - 1) & 1;
    if (c == CHK - 1) {
        // final chunk: contribute log(sum_s beta_{T-1})
        float su = waveSumF(nu0 + nu1 + nu2 + nu3);
        if (lane == 0) sred[wv] = su;
        __syncthreads();
        if (tid == 0) {
            float tot = 0.f;
            #pragma unroll
            for (int i = 0; i < 8; ++i) tot += sred[i];
            OFF += (double)__logf(tot);
            atomicAdd(out, (float)OFF);
        }
    } else {
        // contribute log(max beta_{tEnd-1}) (producer-assigned boundary term)
        if (tid == 0) {
            float mp = wmA[lpar][0];
            #pragma unroll
            for (int i = 1; i < 8; ++i) mp = fmaxf(mp, wmA[lpar][i]);
            OFF += (double)__logf(fmaxf(mp, 1e-30f));
            if (c == 0) OFF += (double)SumAux[0];
            atomicAdd(out, (float)OFF);
        }
    }
}

extern "C" void kernel_launch(void* const* d_in, const int* in_sizes, int n_in,
                              void* d_out, int out_size, void* d_ws, size_t ws_size,
                              hipStream_t stream) {
    const int*   x      = (const int*)  d_in[0];
    const float* lam1   = (const float*)d_in[1];
    const float* lam2   = (const float*)d_in[2];
    const float* lam3   = (const float*)d_in[3];
    const float* logA1  = (const float*)d_in[4];
    const float* logA2  = (const float*)d_in[5];
    const float* logA3  = (const float*)d_in[6];
    const float* logpi1 = (const float*)d_in[7];
    const float* logpi2 = (const float*)d_in[8];
    const float* logpi3 = (const float*)d_in[9];
    float* out = (float*)d_out;

    // ws: [SumAux (256B)] [xf: 1MB] [P_perm: TMAX*2048*2B = 64MB]
    float*  SumAux = (float*)d_ws;
    float*  xf     = (float*)((char*)d_ws + 256);
    ushort* P      = (ushort*)((char*)d_ws + 256 + (size_t)TMAX * MDIM * 4);

    hipMemsetAsync(out, 0, sizeof(float), stream);
    hipMemsetAsync(SumAux, 0, sizeof(float), stream);
    xf_kernel  <<<dim3(256),  dim3(256), 0, stream>>>(x, xf);
    lgam_kernel<<<dim3(256),  dim3(256), 0, stream>>>(x, SumAux);
    emP_kernel <<<dim3(TMAX / 16), dim3(256), 0, stream>>>(xf, lam1, lam2, lam3, P, SumAux);
    fhmm_chunk_kernel<<<dim3(CHK), dim3(512), 0, stream>>>(
        P, SumAux, logA1, logA2, logA3, logpi1, logpi2, logpi3, out);
}

// Round 12
// 207.513 us; speedup vs baseline: 54.8489x; 1.3017x over previous
//
#include <hip/hip_runtime.h>
#include <math.h>

#define TMAX 16384
#define MDIM 16
#define SD   2048
#define CHK  512     // number of parallel chunks
#define CLEN 32      // steps per chunk (CHK*CLEN == TMAX)
#define WUP  32      // warmup steps per chunk (boundary forgetting)

typedef unsigned int  uint;
typedef unsigned short ushort;
typedef __attribute__((ext_vector_type(8))) short short8;
typedef __attribute__((ext_vector_type(4))) short short4v;
typedef __attribute__((ext_vector_type(4))) float floatx4;
typedef __attribute__((ext_vector_type(2))) uint uintx2;

// ---- DPP-based full-wave (64-lane) max ----
template<int CTRL>
__device__ __forceinline__ float fmax_dpp(float v) {
    int o = __builtin_amdgcn_update_dpp(__float_as_int(v), __float_as_int(v),
                                        CTRL, 0xf, 0xf, false);
    return fmaxf(v, __int_as_float(o));
}
__device__ __forceinline__ float waveMax64(float v) {
    v = fmax_dpp<0x111>(v);
    v = fmax_dpp<0x112>(v);
    v = fmax_dpp<0x114>(v);
    v = fmax_dpp<0x118>(v);
    v = fmax_dpp<0x142>(v);
    v = fmax_dpp<0x143>(v);
    return __int_as_float(__builtin_amdgcn_readlane(__float_as_int(v), 63));
}
__device__ __forceinline__ float waveSumF(float v) {
    #pragma unroll
    for (int o = 32; o > 0; o >>= 1) v += __shfl_xor(v, o, 64);
    return v;
}
__device__ __forceinline__ double waveSumD(double v) {
    #pragma unroll
    for (int o = 32; o > 0; o >>= 1) v += __shfl_xor(v, o, 64);
    return v;
}

// bf16 helpers (RNE)
__device__ __forceinline__ short f2bfs(float f) {
    uint u = __float_as_uint(f);
    return (short)((u + 0x7FFFu + ((u >> 16) & 1u)) >> 16);
}
__device__ __forceinline__ uint pkbf(float a, float b) {
    uint ua = __float_as_uint(a), ub = __float_as_uint(b);
    ua = (ua + 0x7FFFu + ((ua >> 16) & 1u)) >> 16;
    ub = (ub + 0x7FFFu + ((ub >> 16) & 1u)) & 0xFFFF0000u;
    return ua | ub;
}
__device__ __forceinline__ short4v pk4(float a, float b, float c, float d) {
    short4v r;
    r[0] = f2bfs(a); r[1] = f2bfs(b); r[2] = f2bfs(c); r[3] = f2bfs(d);
    return r;
}
__device__ __forceinline__ float bfl(uint u) { return __uint_as_float(u << 16); }
__device__ __forceinline__ float bfh(uint u) { return __uint_as_float(u & 0xFFFF0000u); }

// K=16 bf16 MFMA
#if __has_builtin(__builtin_amdgcn_mfma_f32_16x16x16bf16_1k)
#define MFMA16(a, b, c) __builtin_amdgcn_mfma_f32_16x16x16bf16_1k(a, b, c, 0, 0, 0)
#else
__device__ __forceinline__ floatx4 mfma16_asm(short4v a, short4v b, floatx4 c) {
    asm volatile("v_mfma_f32_16x16x16_bf16 %0, %1, %2, %0\n\t"
                 "s_nop 7\n\ts_nop 7"
                 : "+v"(c) : "v"(a), "v"(b));
    return c;
}
#define MFMA16(a, b, c) mfma16_asm(a, b, c)
#endif

// ---- K2: fused pre-pass. 256 blocks x 64 t-steps each.
// P_perm[t][slot] = exp(em - Dem[t]) (bf16), slot order = chunk-kernel ownership;
// SumAux += sum_t Dem[t] - sum_{t,m} lgamma(x+1) (per-block atomicAdd).
__global__ __launch_bounds__(256, 1)
void emP_kernel(const int* __restrict__ x,
                const float* __restrict__ lam1,
                const float* __restrict__ lam2,
                const float* __restrict__ lam3,
                ushort* __restrict__ P,
                float* __restrict__ SumAux) {
    __shared__ float red[4];
    __shared__ float lgtbl[32];
    const int tid = threadIdx.x, lane = tid & 63, wv = tid >> 6;

    if (tid < 32) lgtbl[tid] = lgammaf((float)tid + 1.0f);

    int sidx[8];
    #pragma unroll
    for (int j = 0; j < 8; ++j) {
        int o  = tid * 8 + j;
        int r  = o & 3;
        int ln = (o >> 2) & 63;
        int wk = (o >> 8) & 7;
        int q  = ln >> 4, nn = ln & 15;
        sidx[j] = (4 * q + r) * 128 + 16 * wk + nn;
    }
    float llc[8][16], ls[8];
    #pragma unroll
    for (int j = 0; j < 8; ++j) {
        int s = sidx[j];
        int d1 = s >> 7, d2 = (s >> 3) & 15, d3 = s & 7;
        float sum = 0.f;
        #pragma unroll
        for (int m = 0; m < 16; ++m) {
            float la = lam1[d1*16+m] + lam2[d2*16+m] + lam3[d3*16+m];
            sum += la;
            llc[j][m] = __logf(la);
        }
        ls[j] = sum;
    }
    __syncthreads();   // lgtbl ready

    const int t0 = blockIdx.x * 64;
    // lgamma over this block's 64 t-rows (1024 ints): 1 int4 per thread
    double lg;
    {
        int4 v = ((const int4*)(x + t0 * MDIM))[tid];
        lg = (double)(lgtbl[v.x & 31] + lgtbl[v.y & 31] +
                      lgtbl[v.z & 31] + lgtbl[v.w & 31]);
        lg = waveSumD(lg);
    }

    double sumD = 0.0;
    for (int ti = 0; ti < 64; ++ti) {
        int t = t0 + ti;
        const int* __restrict__ xr = x + t * MDIM;   // uniform -> scalar loads
        float em[8];
        float vm = -3.4e38f;
        #pragma unroll
        for (int j = 0; j < 8; ++j) {
            float d = 0.f;
            #pragma unroll
            for (int m = 0; m < 16; ++m) d = fmaf((float)xr[m], llc[j][m], d);
            em[j] = d - ls[j];
            vm = fmaxf(vm, em[j]);
        }
        vm = waveMax64(vm);
        if (lane == 0) red[wv] = vm;
        __syncthreads();
        float Dem = fmaxf(fmaxf(red[0], red[1]), fmaxf(red[2], red[3]));
        uint4 w;
        w.x = pkbf(__expf(em[0]-Dem), __expf(em[1]-Dem));
        w.y = pkbf(__expf(em[2]-Dem), __expf(em[3]-Dem));
        w.z = pkbf(__expf(em[4]-Dem), __expf(em[5]-Dem));
        w.w = pkbf(__expf(em[6]-Dem), __expf(em[7]-Dem));
        *(uint4*)(P + (size_t)t * SD + tid * 8) = w;
        if (tid == 0) sumD += (double)Dem;
        __syncthreads();
    }
    if (lane == 0 && wv == 0) red[0] = 0.f;
    __syncthreads();
    if (lane == 0) atomicAdd(&red[0], (float)lg);    // block-local combine (LDS)
    __syncthreads();
    if (tid == 0) atomicAdd(SumAux, (float)sumD - red[0]);
}

// ---- K3: CHUNKED forward recurrence. grid = CHK blocks x 512 threads.
// Chunk c: warm-start beta = P_row(t0) at t0 = c*CLEN - WUP (chunk 0: exact pi
// init), run the R10-verified step loop to tEnd-1; accumulate log(max beta) only
// for producer steps >= c*CLEN. Last chunk adds log(sum beta); chunk 0 adds
// SumAux. atomicAdd-combine into out.
__global__ __launch_bounds__(512, 2)
void fhmm_chunk_kernel(const ushort* __restrict__ P,
                       const float* __restrict__ SumAux,
                       const float* __restrict__ logA1,
                       const float* __restrict__ logA2,
                       const float* __restrict__ logA3,
                       const float* __restrict__ logpi1,
                       const float* __restrict__ logpi2,
                       const float* __restrict__ logpi3,
                       float* __restrict__ out)
{
    __shared__ __align__(16) short c1b[2 * 2048];   // parity double buffer
    __shared__ float wmA[2][8];                     // parity double buffer
    __shared__ float sred[8];

    const int tid  = threadIdx.x;
    const int lane = tid & 63;
    const int wv   = tid >> 6;
    const int q    = lane >> 4;
    const int ml   = lane & 15;

    const int c    = blockIdx.x;
    const int tw0  = (c == 0) ? 0 : c * CLEN - WUP;
    const int tEnd = (c + 1) * CLEN;
    const int bAcc = c * CLEN;

    // S1 constants (K=16): B[k=p1=4q+j][n=d1'=ml] = exp(logA1[ml][4q+j])
    short4v bA1k;
    #pragma unroll
    for (int j = 0; j < 4; ++j)
        bA1k[j] = f2bfs(__expf(logA1[ml * 16 + 4 * q + j]));

    // S23 constants, 4 K-chunks: k' = 32jc + 8q + i -> p2 = 4jc+q, p3 = i
    const int d2p = 2 * wv + (ml >> 3);
    const int d3p = ml & 7;
    short8 bK[4];
    #pragma unroll
    for (int jc = 0; jc < 4; ++jc)
        #pragma unroll
        for (int i = 0; i < 8; ++i)
            bK[jc][i] = f2bfs(__expf(logA2[d2p * 16 + 4 * jc + q] + logA3[d3p * 8 + i]));

    // S1 D write offset into c1b[par]  [R9/R10-verified]
    const int oS1w = ml * 128 + ((((2 * wv + (q >> 1)) ^ ml) & 15) << 3) + 4 * (q & 1);
    // S23 A-frag offsets [R9/R10-verified]
    int o23[4];
    #pragma unroll
    for (int jc = 0; jc < 4; ++jc)
        o23[jc] = ml * 128 + ((((4 * jc + q) ^ ml) & 15) << 3);

    // ---- init beta at t = tw0 ----
    double OFF = 0.0;
    float nu0, nu1, nu2, nu3;
    {
        uintx2 p0 = *(const uintx2*)(P + (size_t)tw0 * SD + tid * 4);
        if (c == 0) {   // exact: beta_0 = P_0 * pi
            float lp23 = logpi2[d2p] + logpi3[d3p];
            nu0 = bfl(p0.x) * __expf(logpi1[4 * q + 0] + lp23);
            nu1 = bfh(p0.x) * __expf(logpi1[4 * q + 1] + lp23);
            nu2 = bfl(p0.y) * __expf(logpi1[4 * q + 2] + lp23);
            nu3 = bfh(p0.y) * __expf(logpi1[4 * q + 3] + lp23);
        } else {        // warm-start: beta = P row (arbitrary positive scale)
            nu0 = bfl(p0.x); nu1 = bfh(p0.x);
            nu2 = bfl(p0.y); nu3 = bfh(p0.y);
        }
        float wa = waveMax64(fmaxf(fmaxf(nu0, nu1), fmaxf(nu2, nu3)));
        if (lane == 0) wmA[tw0 & 1][wv] = wa;
        __syncthreads();
    }

    // 2-deep P prefetch
    uintx2 Pb0 = *(const uintx2*)(P + (size_t)(tw0 + 1) * SD + tid * 4);
    uintx2 Pb1 = *(const uintx2*)(P + (size_t)(tw0 + 2) * SD + tid * 4);

    // ---- step loop (R10-verified body + accumulate guard) ----
    for (int t = tw0 + 1; t < tEnd; ++t) {
        const int par = t & 1;
        short* c1cur = c1b + (par << 11);

        // Stage 1 from registers
        {
            short4v af = pk4(nu0, nu1, nu2, nu3);
            floatx4 acc = {0.f, 0.f, 0.f, 0.f};
            acc = MFMA16(af, bA1k, acc);
            ((uintx2*)(c1cur + oS1w))[0] = (uintx2){pkbf(acc[0], acc[1]), pkbf(acc[2], acc[3])};
        }
        __syncthreads();

        int tn = (t + 2 < TMAX) ? t + 2 : TMAX - 1;
        uintx2 Pb2 = *(const uintx2*)(P + (size_t)tn * SD + tid * 4);

        float mp = waveMax64(wmA[par ^ 1][lane & 7]);
        float mg = fmaxf(mp, 1e-30f);
        float inv = __builtin_amdgcn_rcpf(mg);
        if (wv == 0 && lane == 0 && t > bAcc) OFF += (double)__logf(mg);

        // Stage 2+3 fused
        {
            floatx4 a0 = {0.f, 0.f, 0.f, 0.f};
            floatx4 a1 = {0.f, 0.f, 0.f, 0.f};
            a0 = __builtin_amdgcn_mfma_f32_16x16x32_bf16(*(const short8*)(c1cur + o23[0]), bK[0], a0, 0, 0, 0);
            a1 = __builtin_amdgcn_mfma_f32_16x16x32_bf16(*(const short8*)(c1cur + o23[1]), bK[1], a1, 0, 0, 0);
            a0 = __builtin_amdgcn_mfma_f32_16x16x32_bf16(*(const short8*)(c1cur + o23[2]), bK[2], a0, 0, 0, 0);
            a1 = __builtin_amdgcn_mfma_f32_16x16x32_bf16(*(const short8*)(c1cur + o23[3]), bK[3], a1, 0, 0, 0);
            floatx4 acc = a0 + a1;
            nu0 = bfl(Pb0.x) * acc[0] * inv;
            nu1 = bfh(Pb0.x) * acc[1] * inv;
            nu2 = bfl(Pb0.y) * acc[2] * inv;
            nu3 = bfh(Pb0.y) * acc[3] * inv;
            float wa = waveMax64(fmaxf(fmaxf(nu0, nu1), fmaxf(nu2, nu3)));
            if (lane == 0) wmA[par][wv] = wa;
        }
        Pb0 = Pb1; Pb1 = Pb2;
    }
    __syncthreads();

    const int lpar = (tEnd - 1) & 1;
    if (c == CHK - 1) {
        float su = waveSumF(nu0 + nu1 + nu2 + nu3);
        if (lane == 0) sred[wv] = su;
        __syncthreads();
        if (tid == 0) {
            float tot = 0.f;
            #pragma unroll
            for (int i = 0; i < 8; ++i) tot += sred[i];
            OFF += (double)__logf(tot);
            atomicAdd(out, (float)OFF);
        }
    } else {
        if (tid == 0) {
            float mp = wmA[lpar][0];
            #pragma unroll
            for (int i = 1; i < 8; ++i) mp = fmaxf(mp, wmA[lpar][i]);
            OFF += (double)__logf(fmaxf(mp, 1e-30f));
            if (c == 0) OFF += (double)SumAux[0];
            atomicAdd(out, (float)OFF);
        }
    }
}

extern "C" void kernel_launch(void* const* d_in, const int* in_sizes, int n_in,
                              void* d_out, int out_size, void* d_ws, size_t ws_size,
                              hipStream_t stream) {
    const int*   x      = (const int*)  d_in[0];
    const float* lam1   = (const float*)d_in[1];
    const float* lam2   = (const float*)d_in[2];
    const float* lam3   = (const float*)d_in[3];
    const float* logA1  = (const float*)d_in[4];
    const float* logA2  = (const float*)d_in[5];
    const float* logA3  = (const float*)d_in[6];
    const float* logpi1 = (const float*)d_in[7];
    const float* logpi2 = (const float*)d_in[8];
    const float* logpi3 = (const float*)d_in[9];
    float* out = (float*)d_out;

    // ws: [SumAux (256B)] [P_perm: TMAX*2048*2B = 64MB]
    float*  SumAux = (float*)d_ws;
    ushort* P      = (ushort*)((char*)d_ws + 256);

    hipMemsetAsync(out, 0, sizeof(float), stream);
    hipMemsetAsync(SumAux, 0, sizeof(float), stream);
    emP_kernel <<<dim3(TMAX / 64), dim3(256), 0, stream>>>(x, lam1, lam2, lam3, P, SumAux);
    fhmm_chunk_kernel<<<dim3(CHK), dim3(512), 0, stream>>>(
        P, SumAux, logA1, logA2, logA3, logpi1, logpi2, logpi3, out);
}